// Round 1
// baseline (306.810 us; speedup 1.0000x reference)
//
#include <hip/hip_runtime.h>
#include <hip/hip_bf16.h>
#include <cstddef>

// ---------------------------------------------------------------------------
// AttentionBlock: B=2, H=W=64 (S=4096), C=512, GROUPS=32, fp32 in/out.
// Pipeline: GroupNorm -> qkv = xn @ Wqkv + b -> P = softmax(q k^T / sqrt(C))
//           -> o = P v -> out = o @ Wp + bp + x
// All matmuls in bf16 MFMA (16x16x32), fp32 accumulate. Threshold 0.1 absmax.
// ---------------------------------------------------------------------------

typedef __bf16 bf16;
typedef __attribute__((ext_vector_type(8))) __bf16 bf16x8;
typedef __attribute__((ext_vector_type(4))) __bf16 bf16x4;
typedef __attribute__((ext_vector_type(4))) float f32x4;

#define SEQ   4096
#define CCH   512
#define NBAT  2

// ---------------------------------------------------------------------------
// GroupNorm stats: one block per (b, g). 65536 elems each (64x64 spatial x 16 ch).
__global__ __launch_bounds__(256) void gn_stats(const float* __restrict__ x,
                                                float* __restrict__ stats) {
    int bg = blockIdx.x;                  // 0..63
    int b = bg >> 5, g = bg & 31;
    const float* base = x + (size_t)b * SEQ * CCH + g * 16;
    float s = 0.f, ss = 0.f;
    for (int i = threadIdx.x; i < 16384; i += 256) {   // float4 chunks
        int sp = i >> 2, q = i & 3;
        float4 v = *(const float4*)(base + (size_t)sp * CCH + q * 4);
        s  += v.x + v.y + v.z + v.w;
        ss += v.x * v.x + v.y * v.y + v.z * v.z + v.w * v.w;
    }
    #pragma unroll
    for (int o = 32; o > 0; o >>= 1) { s += __shfl_down(s, o); ss += __shfl_down(ss, o); }
    __shared__ float red[2][4];
    int wave = threadIdx.x >> 6, lane = threadIdx.x & 63;
    if (lane == 0) { red[0][wave] = s; red[1][wave] = ss; }
    __syncthreads();
    if (threadIdx.x == 0) {
        float S  = red[0][0] + red[0][1] + red[0][2] + red[0][3];
        float SS = red[1][0] + red[1][1] + red[1][2] + red[1][3];
        float mu = S * (1.f / 65536.f);
        float var = SS * (1.f / 65536.f) - mu * mu;
        stats[bg * 2]     = mu;
        stats[bg * 2 + 1] = rsqrtf(var + 1e-5f);
    }
}

// Normalize + affine + cast to bf16. idx in float4 units over [8192][128].
__global__ __launch_bounds__(256) void gn_apply(const float* __restrict__ x,
                                                const float* __restrict__ stats,
                                                const float* __restrict__ gamma,
                                                const float* __restrict__ beta,
                                                bf16* __restrict__ xn) {
    size_t idx = (size_t)blockIdx.x * 256 + threadIdx.x;
    int c4 = (int)(idx & 127);
    size_t sb = idx >> 7;                 // b*4096 + s
    int b = (int)(sb >> 12);
    int g = c4 >> 2;
    int bg = b * 32 + g;
    float mu = stats[bg * 2], rs = stats[bg * 2 + 1];
    float4 v  = ((const float4*)x)[idx];
    float4 gm = ((const float4*)gamma)[c4];
    float4 bt = ((const float4*)beta)[c4];
    bf16x4 o;
    o[0] = (bf16)((v.x - mu) * rs * gm.x + bt.x);
    o[1] = (bf16)((v.y - mu) * rs * gm.y + bt.y);
    o[2] = (bf16)((v.z - mu) * rs * gm.z + bt.z);
    o[3] = (bf16)((v.w - mu) * rs * gm.w + bt.w);
    ((bf16x4*)xn)[idx] = o;
}

// Transpose-cast weights: W[k][n] fp32 -> Wt[n][k] bf16. z picks Wq/Wk/Wv/Wp.
__global__ __launch_bounds__(256) void wtrans(const float* __restrict__ Wq,
                                              const float* __restrict__ Wk,
                                              const float* __restrict__ Wv,
                                              const float* __restrict__ Wp,
                                              bf16* __restrict__ WqkvT,
                                              bf16* __restrict__ WpT) {
    __shared__ float tile[32][33];
    int z = blockIdx.z;
    const float* W = (z == 0) ? Wq : (z == 1) ? Wk : (z == 2) ? Wv : Wp;
    int tx = threadIdx.x & 31, ty = threadIdx.x >> 5;
    int k0 = blockIdx.x * 32;
    int n0 = blockIdx.y * 32;
    #pragma unroll
    for (int i = ty; i < 32; i += 8)
        tile[i][tx] = W[(size_t)(k0 + i) * CCH + n0 + tx];
    __syncthreads();
    bf16* dst = (z < 3) ? (WqkvT + (size_t)z * CCH * CCH) : WpT;
    #pragma unroll
    for (int i = ty; i < 32; i += 8)
        dst[(size_t)(n0 + i) * CCH + k0 + tx] = (bf16)tile[tx][i];
}

__global__ __launch_bounds__(256) void pack_bias(const float* __restrict__ bq,
                                                 const float* __restrict__ bk,
                                                 const float* __restrict__ bv,
                                                 float* __restrict__ dst) {
    int i = blockIdx.x * 256 + threadIdx.x;
    if (i < 512)       dst[i] = bq[i];
    else if (i < 1024) dst[i] = bk[i - 512];
    else if (i < 1536) dst[i] = bv[i - 1024];
}

// Transpose v slice of qkv [8192][1536] (cols 1024..1535) -> vT [2][512][4096].
__global__ __launch_bounds__(256) void vtrans(const bf16* __restrict__ qkv,
                                              bf16* __restrict__ vT) {
    __shared__ bf16 tile[32][33];
    int b = blockIdx.z;
    int s0 = blockIdx.x * 32, c0 = blockIdx.y * 32;
    int tx = threadIdx.x & 31, ty = threadIdx.x >> 5;
    #pragma unroll
    for (int i = ty; i < 32; i += 8)
        tile[i][tx] = qkv[(size_t)(b * SEQ + s0 + i) * 1536 + 1024 + c0 + tx];
    __syncthreads();
    #pragma unroll
    for (int i = ty; i < 32; i += 8)
        vT[((size_t)b * CCH + c0 + i) * SEQ + s0 + tx] = tile[tx][i];
}

// Row softmax in place on bf16 P rows of length 4096. One block per row.
__global__ __launch_bounds__(256) void softmax_rows(bf16* __restrict__ P) {
    __shared__ float red[8];
    size_t row = blockIdx.x;
    bf16* p = P + row * (size_t)SEQ;
    int t = threadIdx.x;
    bf16x8 h0 = ((bf16x8*)p)[t * 2];
    bf16x8 h1 = ((bf16x8*)p)[t * 2 + 1];
    float v[16];
    #pragma unroll
    for (int i = 0; i < 8; ++i) { v[i] = (float)h0[i]; v[8 + i] = (float)h1[i]; }
    float mx = v[0];
    #pragma unroll
    for (int i = 1; i < 16; ++i) mx = fmaxf(mx, v[i]);
    #pragma unroll
    for (int o = 32; o > 0; o >>= 1) mx = fmaxf(mx, __shfl_down(mx, o));
    int wave = t >> 6, lane = t & 63;
    if (lane == 0) red[wave] = mx;
    __syncthreads();
    mx = fmaxf(fmaxf(red[0], red[1]), fmaxf(red[2], red[3]));
    float sum = 0.f;
    #pragma unroll
    for (int i = 0; i < 16; ++i) { v[i] = __expf(v[i] - mx); sum += v[i]; }
    #pragma unroll
    for (int o = 32; o > 0; o >>= 1) sum += __shfl_down(sum, o);
    if (lane == 0) red[4 + wave] = sum;
    __syncthreads();
    sum = red[4] + red[5] + red[6] + red[7];
    float inv = 1.f / sum;
    #pragma unroll
    for (int i = 0; i < 8; ++i) { h0[i] = (bf16)(v[i] * inv); h1[i] = (bf16)(v[8 + i] * inv); }
    ((bf16x8*)p)[t * 2]     = h0;
    ((bf16x8*)p)[t * 2 + 1] = h1;
}

// ---------------------------------------------------------------------------
// bf16 B^T-layout GEMM, m97 structure: 128x128 tile, BK=32, 256 threads,
// global_load_lds width 16, 16x16x32 MFMA, 4x4 acc per wave.
// C[m][n] = sum_k A[m][k] * Bt[n][k], epilogue per EPI:
//   0: bf16 = acc + bias[n]       (QKV)
//   1: bf16 = acc * scale         (QK^T logits)
//   2: bf16 = acc                 (PV)
//   3: f32  = acc + bias[n] + resid[m*512+n]   (out proj + residual)
template <int EPI>
__global__ __launch_bounds__(256, 2) void gemm_bt(
    const bf16* __restrict__ A, long long aBatch, int lda,
    const bf16* __restrict__ Bt, long long bBatch, int ldb,
    void* __restrict__ Cout, long long cBatch, int ldc,
    int K, float scale, const float* __restrict__ bias,
    const float* __restrict__ resid) {
    __shared__ __align__(16) bf16 As[128 * 32];
    __shared__ __align__(16) bf16 Bs[128 * 32];
    const int tid = threadIdx.x;
    const int lane = tid & 63;
    const int wave = tid >> 6;
    const long long m0 = (long long)blockIdx.x * 128;
    const long long n0 = (long long)blockIdx.y * 128;
    const bf16* Ab = A + (long long)blockIdx.z * aBatch;
    const bf16* Bb = Bt + (long long)blockIdx.z * bBatch;

    const int wm = (wave & 1) * 64;
    const int wn = (wave >> 1) * 64;
    const int fm = lane & 15;
    const int kb = (lane >> 4) * 8;

    f32x4 acc[4][4];
    #pragma unroll
    for (int i = 0; i < 4; ++i)
        #pragma unroll
        for (int j = 0; j < 4; ++j)
            acc[i][j] = (f32x4){0.f, 0.f, 0.f, 0.f};

    const int r0 = tid >> 2;            // staging row (0..63)
    const int koff = (tid & 3) * 8;     // staging k offset

    for (int k0 = 0; k0 < K; k0 += 32) {
        const bf16* ga0 = Ab + (m0 + r0) * (long long)lda + k0 + koff;
        const bf16* ga1 = Ab + (m0 + r0 + 64) * (long long)lda + k0 + koff;
        const bf16* gb0 = Bb + (n0 + r0) * (long long)ldb + k0 + koff;
        const bf16* gb1 = Bb + (n0 + r0 + 64) * (long long)ldb + k0 + koff;
        __builtin_amdgcn_global_load_lds((const __attribute__((address_space(1))) void*)ga0,
                                         (__attribute__((address_space(3))) void*)&As[tid * 8], 16, 0, 0);
        __builtin_amdgcn_global_load_lds((const __attribute__((address_space(1))) void*)ga1,
                                         (__attribute__((address_space(3))) void*)&As[(tid + 256) * 8], 16, 0, 0);
        __builtin_amdgcn_global_load_lds((const __attribute__((address_space(1))) void*)gb0,
                                         (__attribute__((address_space(3))) void*)&Bs[tid * 8], 16, 0, 0);
        __builtin_amdgcn_global_load_lds((const __attribute__((address_space(1))) void*)gb1,
                                         (__attribute__((address_space(3))) void*)&Bs[(tid + 256) * 8], 16, 0, 0);
        __syncthreads();
        bf16x8 fa[4], fb[4];
        #pragma unroll
        for (int i = 0; i < 4; ++i)
            fa[i] = *(const bf16x8*)&As[(wm + i * 16 + fm) * 32 + kb];
        #pragma unroll
        for (int j = 0; j < 4; ++j)
            fb[j] = *(const bf16x8*)&Bs[(wn + j * 16 + fm) * 32 + kb];
        #pragma unroll
        for (int i = 0; i < 4; ++i)
            #pragma unroll
            for (int j = 0; j < 4; ++j)
                acc[i][j] = __builtin_amdgcn_mfma_f32_16x16x32_bf16(fa[i], fb[j], acc[i][j], 0, 0, 0);
        __syncthreads();
    }

    // Epilogue. C/D layout: col = lane&15, row = (lane>>4)*4 + reg  [verified m89/m91]
    const int col = lane & 15;
    const int rowb = (lane >> 4) * 4;
    #pragma unroll
    for (int i = 0; i < 4; ++i) {
        #pragma unroll
        for (int j = 0; j < 4; ++j) {
            long long mg = m0 + wm + i * 16 + rowb;
            long long ng = n0 + wn + j * 16 + col;
            #pragma unroll
            for (int r = 0; r < 4; ++r) {
                float v = acc[i][j][r];
                long long m = mg + r;
                long long cidx = (long long)blockIdx.z * cBatch + m * (long long)ldc + ng;
                if constexpr (EPI == 0) {
                    ((bf16*)Cout)[cidx] = (bf16)(v + bias[ng]);
                } else if constexpr (EPI == 1) {
                    ((bf16*)Cout)[cidx] = (bf16)(v * scale);
                } else if constexpr (EPI == 2) {
                    ((bf16*)Cout)[cidx] = (bf16)v;
                } else {
                    ((float*)Cout)[cidx] = v + bias[ng] + resid[m * CCH + ng];
                }
            }
        }
    }
}

// ---------------------------------------------------------------------------
extern "C" void kernel_launch(void* const* d_in, const int* in_sizes, int n_in,
                              void* d_out, int out_size, void* d_ws, size_t ws_size,
                              hipStream_t stream) {
    const float* x     = (const float*)d_in[0];
    const float* gamma = (const float*)d_in[1];
    const float* beta  = (const float*)d_in[2];
    const float* Wq    = (const float*)d_in[3];
    const float* bq    = (const float*)d_in[4];
    const float* Wk    = (const float*)d_in[5];
    const float* bk    = (const float*)d_in[6];
    const float* Wv    = (const float*)d_in[7];
    const float* bv    = (const float*)d_in[8];
    const float* Wp    = (const float*)d_in[9];
    const float* bp    = (const float*)d_in[10];
    float* out = (float*)d_out;

    // Workspace layout (bytes, 256-aligned)
    constexpr size_t OFF_STATS = 0;          //   512 B  (mean,rstd per b*32+g)
    constexpr size_t OFF_BIAS  = 1024;       //  6144 B  packed qkv bias fp32
    constexpr size_t OFF_WQKVT = 8192;       //  1.5 MB  [1536][512] bf16
    constexpr size_t OFF_WPT   = 1581056;    //  0.5 MB  [512][512] bf16
    constexpr size_t OFF_XN    = 2105344;    //  8.0 MB  xn bf16 [8192][512]; reused as o
    constexpr size_t OFF_QKV   = 10493952;   // 24.0 MB  [8192][1536] bf16
    constexpr size_t OFF_VT    = 35659776;   //  8.0 MB  vT [2][512][4096] bf16
    constexpr size_t OFF_P     = 44048384;   // 64 MB (both batches) or 32 MB (per-batch)
    constexpr size_t NEED_FULL = OFF_P + (size_t)NBAT * SEQ * SEQ * 2;

    char* ws = (char*)d_ws;
    float* stats   = (float*)(ws + OFF_STATS);
    float* biasQKV = (float*)(ws + OFF_BIAS);
    bf16*  WqkvT   = (bf16*)(ws + OFF_WQKVT);
    bf16*  WpT     = (bf16*)(ws + OFF_WPT);
    bf16*  xn      = (bf16*)(ws + OFF_XN);
    bf16*  qkv     = (bf16*)(ws + OFF_QKV);
    bf16*  vT      = (bf16*)(ws + OFF_VT);
    bf16*  P       = (bf16*)(ws + OFF_P);
    bf16*  o       = xn;   // xn dead after QKV GEMM

    const float scale = 0.044194173824159216f;  // 1/sqrt(512)

    gn_stats<<<64, 256, 0, stream>>>(x, stats);
    gn_apply<<<4096, 256, 0, stream>>>(x, stats, gamma, beta, xn);
    wtrans<<<dim3(16, 16, 4), 256, 0, stream>>>(Wq, Wk, Wv, Wp, WqkvT, WpT);
    pack_bias<<<6, 256, 0, stream>>>(bq, bk, bv, biasQKV);

    // qkv = xn @ WqkvT^T + bias : M=8192, N=1536, K=512
    gemm_bt<0><<<dim3(64, 12, 1), 256, 0, stream>>>(
        xn, 0, CCH, WqkvT, 0, CCH, qkv, 0, 1536, CCH, 1.f, biasQKV, nullptr);
    vtrans<<<dim3(128, 16, NBAT), 256, 0, stream>>>(qkv, vT);

    if (ws_size >= NEED_FULL) {
        // Both batches in one pass (grid.z = 2)
        gemm_bt<1><<<dim3(32, 32, NBAT), 256, 0, stream>>>(
            qkv, (long long)SEQ * 1536, 1536, qkv + 512, (long long)SEQ * 1536, 1536,
            P, (long long)SEQ * SEQ, SEQ, CCH, scale, nullptr, nullptr);
        softmax_rows<<<NBAT * SEQ, 256, 0, stream>>>(P);
        gemm_bt<2><<<dim3(32, 4, NBAT), 256, 0, stream>>>(
            P, (long long)SEQ * SEQ, SEQ, vT, (long long)CCH * SEQ, SEQ,
            o, (long long)SEQ * CCH, CCH, SEQ, 1.f, nullptr, nullptr);
    } else {
        // Per-batch, reusing one 32 MB P buffer
        for (int b = 0; b < NBAT; ++b) {
            const bf16* qb = qkv + (long long)b * SEQ * 1536;
            gemm_bt<1><<<dim3(32, 32, 1), 256, 0, stream>>>(
                qb, 0, 1536, qb + 512, 0, 1536, P, 0, SEQ, CCH, scale, nullptr, nullptr);
            softmax_rows<<<SEQ, 256, 0, stream>>>(P);
            gemm_bt<2><<<dim3(32, 4, 1), 256, 0, stream>>>(
                P, 0, SEQ, vT + (long long)b * CCH * SEQ, 0, SEQ,
                o + (long long)b * SEQ * CCH, 0, CCH, SEQ, 1.f, nullptr, nullptr);
        }
    }

    // out = o @ WpT^T + bp + x : M=8192, N=512, K=512, fp32 out
    gemm_bt<3><<<dim3(64, 4, 1), 256, 0, stream>>>(
        o, 0, CCH, WpT, 0, CCH, out, 0, CCH, CCH, 1.f, bp, x);
}